// Round 2
// baseline (2732.208 us; speedup 1.0000x reference)
//
#include <hip/hip_runtime.h>
#include <math.h>

#define D_ 1024
#define S_ 4096
#define B_ 4
#define NB 16
#define BS 256
#define NH 16
#define HD 64

// ---------------- block means: xb[b*16+n][d] = mean over 256 rows ----------------
__global__ __launch_bounds__(256) void block_mean_kernel(const float* __restrict__ x,
                                                         float* __restrict__ xb) {
  int bid = blockIdx.x;            // b*16 + n
  int b = bid >> 4, n = bid & 15;
  int t = threadIdx.x;
  float4 acc = {0.f, 0.f, 0.f, 0.f};
  const float* xp = x + ((long)(n * BS) * B_ + b) * D_ + t * 4;
  for (int s = 0; s < BS; ++s) {
    float4 u = *(const float4*)xp;
    acc.x += u.x; acc.y += u.y; acc.z += u.z; acc.w += u.w;
    xp += B_ * D_;
  }
  float* o = xb + bid * D_ + t * 4;
  o[0] = acc.x * (1.f / BS); o[1] = acc.y * (1.f / BS);
  o[2] = acc.z * (1.f / BS); o[3] = acc.w * (1.f / BS);
}

// ---------------- q_blk / k_blk: (64x1024) = xb @ W^T + b, fp32 ----------------
__global__ __launch_bounds__(256) void qkblk_kernel(const float* __restrict__ xb,
    const float* __restrict__ Wq, const float* __restrict__ bq,
    const float* __restrict__ Wk, const float* __restrict__ bk,
    float* __restrict__ qb, float* __restrict__ kb) {
  int bidx = blockIdx.x;           // 0..63 q rows, 64..127 k rows
  int row = bidx & 63;
  const float* W  = (bidx & 64) ? Wk : Wq;
  const float* bi = (bidx & 64) ? bk : bq;
  float* out      = (bidx & 64) ? kb : qb;
  __shared__ float xs[D_];
  int t = threadIdx.x;
#pragma unroll
  for (int j = 0; j < 4; ++j) xs[t + j * 256] = xb[row * D_ + t + j * 256];
  __syncthreads();
  int w = t >> 6, lane = t & 63;
  for (int jj = 0; jj < 256; ++jj) {
    int j = jj * 4 + w;
    float acc = 0.f;
    const float* wp = W + (long)j * D_ + lane;
#pragma unroll
    for (int kk = 0; kk < 16; ++kk) acc += xs[kk * 64 + lane] * wp[kk * 64];
#pragma unroll
    for (int m = 1; m < 64; m <<= 1) acc += __shfl_xor(acc, m);
    if (lane == 0) out[row * D_ + j] = acc + bi[j];
  }
}

// ---------------- logits[b][n][m] = dot(q_blk, k_blk)/32, fp32 ----------------
__global__ __launch_bounds__(256) void logits_kernel(const float* __restrict__ qb,
                                                     const float* __restrict__ kb,
                                                     float* __restrict__ lg) {
  int idx = blockIdx.x * 4 + (threadIdx.x >> 6);   // 0..1023 = b*256+n*16+m
  int b = idx >> 8, n = (idx >> 4) & 15, m = idx & 15;
  int lane = threadIdx.x & 63;
  float acc = 0.f;
  const float* qp = qb + (b * 16 + n) * D_ + lane;
  const float* kp = kb + (b * 16 + m) * D_ + lane;
#pragma unroll
  for (int kk = 0; kk < 16; ++kk) acc += qp[kk * 64] * kp[kk * 64];
#pragma unroll
  for (int mm = 1; mm < 64; mm <<= 1) acc += __shfl_xor(acc, mm);
  if (lane == 0) lg[idx] = acc * (1.f / 32.f);
}

// ---------------- Sinkhorn (5 iters) + row argmax -> perm ----------------
__global__ __launch_bounds__(256) void sinkhorn_kernel(const float* __restrict__ lg,
                                                       int* __restrict__ perm) {
  int b = blockIdx.x;
  __shared__ float L[16][17];
  int t = threadIdx.x;
  int n = t >> 4, m = t & 15;
  if (t < 256) L[n][m] = lg[b * 256 + t];
  __syncthreads();
  for (int it = 0; it < 5; ++it) {
    float mx = -3e38f;
#pragma unroll
    for (int i = 0; i < 16; ++i) mx = fmaxf(mx, L[n][i]);
    float sm = 0.f;
#pragma unroll
    for (int i = 0; i < 16; ++i) sm += expf(L[n][i] - mx);
    float lse = mx + logf(sm);
    __syncthreads();
    L[n][m] -= lse;
    __syncthreads();
    mx = -3e38f;
#pragma unroll
    for (int i = 0; i < 16; ++i) mx = fmaxf(mx, L[i][m]);
    sm = 0.f;
#pragma unroll
    for (int i = 0; i < 16; ++i) sm += expf(L[i][m] - mx);
    lse = mx + logf(sm);
    __syncthreads();
    L[n][m] -= lse;
    __syncthreads();
  }
  if (t < 16) {
    float best = -3e38f; int bi = 0;
#pragma unroll
    for (int i = 0; i < 16; ++i) {
      float v = L[t][i];
      if (v > best) { best = v; bi = i; }
    }
    perm[b * 16 + t] = bi;   // first-max, matches jnp.argmax
  }
}

// ---------------- fp32 tiled GEMM: C = A @ W^T + bias, 128x128x16 ----------------
// mode 0: A = x (S,B,D) with per-block perm gather (batch b); C = per-b (S,D), z in {0,1,2}
// mode 1: A = per-b (S,D); C = out (S,B,D) at batch b, z = 0
__global__ __launch_bounds__(256, 2) void gemm_f32_kernel(
    const float* __restrict__ A0,
    const float* __restrict__ W0, const float* __restrict__ W1, const float* __restrict__ W2,
    const float* __restrict__ bi0, const float* __restrict__ bi1, const float* __restrict__ bi2,
    float* __restrict__ O0, float* __restrict__ O1, float* __restrict__ O2,
    const int* __restrict__ perm, int b, int mode) {
  int z = blockIdx.z;
  const float* W  = (z == 0) ? W0 : (z == 1 ? W1 : W2);
  const float* bi = (z == 0) ? bi0 : (z == 1 ? bi1 : bi2);
  float* C        = (z == 0) ? O0 : (z == 1 ? O1 : O2);
  int st = blockIdx.y;                 // 128-row tile among 32 (4096 rows)
  int col0 = blockIdx.x * 128;
  const float* abase; float* cbase; long a_stride, c_stride;
  if (mode == 0) {
    int n = st >> 1;
    int sb = perm[b * NB + n];
    long a_row0 = (long)sb * BS + (st & 1) * 128;
    abase = A0 + (a_row0 * B_ + b) * D_;
    a_stride = (long)B_ * D_;
    cbase = C + (long)(st * 128) * D_;
    c_stride = D_;
  } else {
    abase = A0 + (long)(st * 128) * D_;
    a_stride = D_;
    cbase = C + ((long)(st * 128) * B_ + b) * D_;
    c_stride = (long)B_ * D_;
  }
  __shared__ float As[16][132];
  __shared__ float Bs[16][132];
  int t = threadIdx.x;
  int lr = t >> 1, kq = (t & 1) * 8;   // staging: row lr, k-offset kq
  int m0 = (t >> 4) * 8, n0 = (t & 15) * 8;
  const float* aptr = abase + (long)lr * a_stride + kq;
  const float* bptr = W + (long)(col0 + lr) * D_ + kq;
  float acc[8][8];
#pragma unroll
  for (int i = 0; i < 8; ++i)
#pragma unroll
    for (int j = 0; j < 8; ++j) acc[i][j] = 0.f;

  for (int kt = 0; kt < D_ / 16; ++kt) {
    float4 av0 = *(const float4*)(aptr);
    float4 av1 = *(const float4*)(aptr + 4);
    float4 bv0 = *(const float4*)(bptr);
    float4 bv1 = *(const float4*)(bptr + 4);
    aptr += 16; bptr += 16;
    __syncthreads();
    As[kq + 0][lr] = av0.x; As[kq + 1][lr] = av0.y;
    As[kq + 2][lr] = av0.z; As[kq + 3][lr] = av0.w;
    As[kq + 4][lr] = av1.x; As[kq + 5][lr] = av1.y;
    As[kq + 6][lr] = av1.z; As[kq + 7][lr] = av1.w;
    Bs[kq + 0][lr] = bv0.x; Bs[kq + 1][lr] = bv0.y;
    Bs[kq + 2][lr] = bv0.z; Bs[kq + 3][lr] = bv0.w;
    Bs[kq + 4][lr] = bv1.x; Bs[kq + 5][lr] = bv1.y;
    Bs[kq + 6][lr] = bv1.z; Bs[kq + 7][lr] = bv1.w;
    __syncthreads();
#pragma unroll
    for (int k = 0; k < 16; ++k) {
      float4 a0 = *(const float4*)&As[k][m0];
      float4 a1 = *(const float4*)&As[k][m0 + 4];
      float4 b0 = *(const float4*)&Bs[k][n0];
      float4 b1 = *(const float4*)&Bs[k][n0 + 4];
      float aa[8] = {a0.x, a0.y, a0.z, a0.w, a1.x, a1.y, a1.z, a1.w};
      float bb[8] = {b0.x, b0.y, b0.z, b0.w, b1.x, b1.y, b1.z, b1.w};
#pragma unroll
      for (int i = 0; i < 8; ++i)
#pragma unroll
        for (int j = 0; j < 8; ++j) acc[i][j] += aa[i] * bb[j];
    }
  }
  float bb[8];
#pragma unroll
  for (int j = 0; j < 8; ++j) bb[j] = bi[col0 + n0 + j];
#pragma unroll
  for (int i = 0; i < 8; ++i) {
    float* cp = cbase + (long)(m0 + i) * c_stride + col0 + n0;
    float4 c0 = {acc[i][0] + bb[0], acc[i][1] + bb[1], acc[i][2] + bb[2], acc[i][3] + bb[3]};
    float4 c1 = {acc[i][4] + bb[4], acc[i][5] + bb[5], acc[i][6] + bb[6], acc[i][7] + bb[7]};
    *(float4*)(cp) = c0;
    *(float4*)(cp + 4) = c1;
  }
}

// ---------------- block-local attention (per b), fp32, online softmax ----------------
// grid 256 = (n,h); 256 threads = one query row each. O aliases Q (safe: each
// block writes exactly the q-slice only it reads, after reading it).
__global__ __launch_bounds__(256, 2) void attn_f32_kernel(
    float* __restrict__ Q, const float* __restrict__ K, const float* __restrict__ V) {
  int n = blockIdx.x >> 4, h = blockIdx.x & 15;
  int t = threadIdx.x;
  __shared__ float Kc[64][68];
  __shared__ float Vc[64][68];
  // load q row into registers
  float4 qv[16];
  const float* qrow = Q + ((long)(n * BS) + t) * D_ + h * HD;
#pragma unroll
  for (int e = 0; e < 16; ++e) qv[e] = *(const float4*)(qrow + e * 4);
  float m = -3e38f, l = 0.f;
  float4 o4[16];
#pragma unroll
  for (int e = 0; e < 16; ++e) o4[e] = {0.f, 0.f, 0.f, 0.f};

  int sj = t >> 2, se = (t & 3) * 16;       // staging: key sj, dims se..se+15
  for (int c = 0; c < 4; ++c) {
    __syncthreads();
    const float* kp = K + ((long)(n * BS + c * 64 + sj)) * D_ + h * HD + se;
    const float* vp = V + ((long)(n * BS + c * 64 + sj)) * D_ + h * HD + se;
#pragma unroll
    for (int i = 0; i < 4; ++i) {
      *(float4*)&Kc[sj][se + i * 4] = *(const float4*)(kp + i * 4);
      *(float4*)&Vc[sj][se + i * 4] = *(const float4*)(vp + i * 4);
    }
    __syncthreads();
    for (int j = 0; j < 64; ++j) {
      float s = 0.f;
#pragma unroll
      for (int e = 0; e < 16; ++e) {
        float4 kv = *(const float4*)&Kc[j][e * 4];
        s += qv[e].x * kv.x + qv[e].y * kv.y + qv[e].z * kv.z + qv[e].w * kv.w;
      }
      s *= 0.125f;
      if (s > m) {
        float sc = __expf(m - s);
        l *= sc;
#pragma unroll
        for (int e = 0; e < 16; ++e) {
          o4[e].x *= sc; o4[e].y *= sc; o4[e].z *= sc; o4[e].w *= sc;
        }
        m = s;
      }
      float p = __expf(s - m);
      l += p;
#pragma unroll
      for (int e = 0; e < 16; ++e) {
        float4 vv = *(const float4*)&Vc[j][e * 4];
        o4[e].x += p * vv.x; o4[e].y += p * vv.y;
        o4[e].z += p * vv.z; o4[e].w += p * vv.w;
      }
    }
  }
  float inv = 1.f / l;
  float* orow = Q + ((long)(n * BS) + t) * D_ + h * HD;
#pragma unroll
  for (int e = 0; e < 16; ++e) {
    float4 ov = {o4[e].x * inv, o4[e].y * inv, o4[e].z * inv, o4[e].w * inv};
    *(float4*)(orow + e * 4) = ov;
  }
}

// ---------------- launch ----------------
extern "C" void kernel_launch(void* const* d_in, const int* in_sizes, int n_in,
                              void* d_out, int out_size, void* d_ws, size_t ws_size,
                              hipStream_t stream) {
  (void)in_sizes; (void)n_in; (void)out_size; (void)ws_size;
  const float* x  = (const float*)d_in[0];
  const float* Wq = (const float*)d_in[1];
  const float* bq = (const float*)d_in[2];
  const float* Wk = (const float*)d_in[3];
  const float* bk = (const float*)d_in[4];
  const float* Wv = (const float*)d_in[5];
  const float* bv = (const float*)d_in[6];
  const float* Wo = (const float*)d_in[7];
  const float* bo = (const float*)d_in[8];
  float* out = (float*)d_out;
  char* ws = (char*)d_ws;

  float* xbf  = (float*)(ws);                   // 64x1024 f32
  float* qbf  = (float*)(ws + 262144);
  float* kbf  = (float*)(ws + 524288);
  float* lgf  = (float*)(ws + 786432);          // 4x16x16
  int*   perm = (int*)(ws + 790528);            // 64 ints
  float* Qb   = (float*)(ws + (1 << 20));       // per-b (S,D) f32, 16 MB each
  float* Kb   = Qb + (size_t)S_ * D_;
  float* Vb   = Kb + (size_t)S_ * D_;

  block_mean_kernel<<<64, 256, 0, stream>>>(x, xbf);
  qkblk_kernel<<<128, 256, 0, stream>>>(xbf, Wq, bq, Wk, bk, qbf, kbf);
  logits_kernel<<<256, 256, 0, stream>>>(qbf, kbf, lgf);
  sinkhorn_kernel<<<4, 256, 0, stream>>>(lgf, perm);
  for (int b = 0; b < B_; ++b) {
    gemm_f32_kernel<<<dim3(8, 32, 3), 256, 0, stream>>>(
        x, Wq, Wk, Wv, bq, bk, bv, Qb, Kb, Vb, perm, b, 0);
    attn_f32_kernel<<<256, 256, 0, stream>>>(Qb, Kb, Vb);
    gemm_f32_kernel<<<dim3(8, 32, 1), 256, 0, stream>>>(
        Qb, Wo, Wo, Wo, bo, bo, bo, out, out, out, perm, b, 1);
  }
}

// Round 3
// 1585.226 us; speedup vs baseline: 1.7235x; 1.7235x over previous
//
#include <hip/hip_runtime.h>
#include <math.h>

typedef unsigned short u16;
typedef __bf16 bf16t;
typedef bf16t bf16x8 __attribute__((ext_vector_type(8)));
typedef float f32x4 __attribute__((ext_vector_type(4)));

#define D_ 1024
#define S_ 4096
#define B_ 4
#define NB 16
#define BS 256
#define NH 16
#define HD 64

__device__ __forceinline__ float bfu2f(u16 u) {
  unsigned int x = ((unsigned int)u) << 16;
  float f; __builtin_memcpy(&f, &x, 4); return f;
}
__device__ __forceinline__ u16 f2bfu(float f) {
  unsigned int x; __builtin_memcpy(&x, &f, 4);
  x += 0x7fffu + ((x >> 16) & 1u);   // RNE
  return (u16)(x >> 16);
}
__device__ __forceinline__ void gld_lds16(const void* g, void* l) {
  __builtin_amdgcn_global_load_lds((__attribute__((address_space(1))) void*)g,
                                   (__attribute__((address_space(3))) void*)l, 16, 0, 0);
}

// ---------------- block means ----------------
__global__ __launch_bounds__(256) void block_mean_kernel(const float* __restrict__ x,
                                                         float* __restrict__ xb) {
  int bid = blockIdx.x;            // b*16 + n
  int b = bid >> 4, n = bid & 15;
  int t = threadIdx.x;
  float4 acc = {0.f, 0.f, 0.f, 0.f};
  const float* xp = x + ((long)(n * BS) * B_ + b) * D_ + t * 4;
  for (int s = 0; s < BS; ++s) {
    float4 u = *(const float4*)xp;
    acc.x += u.x; acc.y += u.y; acc.z += u.z; acc.w += u.w;
    xp += B_ * D_;
  }
  float* o = xb + bid * D_ + t * 4;
  o[0] = acc.x * (1.f / BS); o[1] = acc.y * (1.f / BS);
  o[2] = acc.z * (1.f / BS); o[3] = acc.w * (1.f / BS);
}

// ---------------- q_blk / k_blk ----------------
__global__ __launch_bounds__(256) void qkblk_kernel(const float* __restrict__ xb,
    const float* __restrict__ Wq, const float* __restrict__ bq,
    const float* __restrict__ Wk, const float* __restrict__ bk,
    float* __restrict__ qb, float* __restrict__ kb) {
  int bidx = blockIdx.x;
  int row = bidx & 63;
  const float* W  = (bidx & 64) ? Wk : Wq;
  const float* bi = (bidx & 64) ? bk : bq;
  float* out      = (bidx & 64) ? kb : qb;
  __shared__ float xs[D_];
  int t = threadIdx.x;
#pragma unroll
  for (int j = 0; j < 4; ++j) xs[t + j * 256] = xb[row * D_ + t + j * 256];
  __syncthreads();
  int w = t >> 6, lane = t & 63;
  for (int jj = 0; jj < 256; ++jj) {
    int j = jj * 4 + w;
    float acc = 0.f;
    const float* wp = W + (long)j * D_ + lane;
#pragma unroll
    for (int kk = 0; kk < 16; ++kk) acc += xs[kk * 64 + lane] * wp[kk * 64];
#pragma unroll
    for (int m = 1; m < 64; m <<= 1) acc += __shfl_xor(acc, m);
    if (lane == 0) out[row * D_ + j] = acc + bi[j];
  }
}

// ---------------- logits ----------------
__global__ __launch_bounds__(256) void logits_kernel(const float* __restrict__ qb,
                                                     const float* __restrict__ kb,
                                                     float* __restrict__ lg) {
  int idx = blockIdx.x * 4 + (threadIdx.x >> 6);
  int b = idx >> 8, n = (idx >> 4) & 15, m = idx & 15;
  int lane = threadIdx.x & 63;
  float acc = 0.f;
  const float* qp = qb + (b * 16 + n) * D_ + lane;
  const float* kp = kb + (b * 16 + m) * D_ + lane;
#pragma unroll
  for (int kk = 0; kk < 16; ++kk) acc += qp[kk * 64] * kp[kk * 64];
#pragma unroll
  for (int mm = 1; mm < 64; mm <<= 1) acc += __shfl_xor(acc, mm);
  if (lane == 0) lg[idx] = acc * (1.f / 32.f);
}

// ---------------- Sinkhorn + argmax ----------------
__global__ __launch_bounds__(256) void sinkhorn_kernel(const float* __restrict__ lg,
                                                       int* __restrict__ perm) {
  int b = blockIdx.x;
  __shared__ float L[16][17];
  int t = threadIdx.x;
  int n = t >> 4, m = t & 15;
  if (t < 256) L[n][m] = lg[b * 256 + t];
  __syncthreads();
  for (int it = 0; it < 5; ++it) {
    float mx = -3e38f;
#pragma unroll
    for (int i = 0; i < 16; ++i) mx = fmaxf(mx, L[n][i]);
    float sm = 0.f;
#pragma unroll
    for (int i = 0; i < 16; ++i) sm += expf(L[n][i] - mx);
    float lse = mx + logf(sm);
    __syncthreads();
    L[n][m] -= lse;
    __syncthreads();
    mx = -3e38f;
#pragma unroll
    for (int i = 0; i < 16; ++i) mx = fmaxf(mx, L[i][m]);
    sm = 0.f;
#pragma unroll
    for (int i = 0; i < 16; ++i) sm += expf(L[i][m] - mx);
    lse = mx + logf(sm);
    __syncthreads();
    L[n][m] -= lse;
    __syncthreads();
  }
  if (t < 16) {
    float best = -3e38f; int bi = 0;
#pragma unroll
    for (int i = 0; i < 16; ++i) {
      float v = L[t][i];
      if (v > best) { best = v; bi = i; }
    }
    perm[b * 16 + t] = bi;
  }
}

// ---------------- fp32 -> bf16 hi/lo split ----------------
__global__ __launch_bounds__(256) void split_kernel(const float* __restrict__ in,
    u16* __restrict__ hi, u16* __restrict__ lo, int n4) {
  int i = blockIdx.x * 256 + threadIdx.x;
  if (i >= n4) return;
  float4 v = ((const float4*)in)[i];
  ushort4 h, l;
  h.x = f2bfu(v.x); l.x = f2bfu(v.x - bfu2f(h.x));
  h.y = f2bfu(v.y); l.y = f2bfu(v.y - bfu2f(h.y));
  h.z = f2bfu(v.z); l.z = f2bfu(v.z - bfu2f(h.z));
  h.w = f2bfu(v.w); l.w = f2bfu(v.w - bfu2f(h.w));
  ((ushort4*)hi)[i] = h;
  ((ushort4*)lo)[i] = l;
}

// ---------------- split-bf16 MFMA GEMM: C = A @ W^T + bias (fp32-accurate) -------
// mode 0: A = x hi/lo (S,B,D) with perm gather; C[z] = (B,S,D) fp32, z in 0..2
// mode 1: A = (B,S,D) hi/lo; C = out (S,B,D) fp32, z = 0
// bfix >= 0: per-batch dispatch (blockIdx.y = st); else b = blockIdx.y>>5.
__global__ __launch_bounds__(256, 2) void gemm_split_kernel(
    const u16* __restrict__ Ahi, const u16* __restrict__ Alo,
    const u16* __restrict__ Whi, const u16* __restrict__ Wlo,
    const float* __restrict__ bi0, const float* __restrict__ bi1, const float* __restrict__ bi2,
    float* __restrict__ O0, float* __restrict__ O1, float* __restrict__ O2,
    const int* __restrict__ perm, int mode, int bfix) {
  int z = blockIdx.z;
  const u16* Wh = Whi + (size_t)z * (D_ * D_);
  const u16* Wl = Wlo + (size_t)z * (D_ * D_);
  const float* bi = (z == 0) ? bi0 : (z == 1 ? bi1 : bi2);
  float* C        = (z == 0) ? O0 : (z == 1 ? O1 : O2);
  int b, st;
  if (bfix >= 0) { b = bfix; st = blockIdx.y; }
  else           { b = blockIdx.y >> 5; st = blockIdx.y & 31; }
  int col0 = blockIdx.x * 128;
  long a_off, a_stride, c_stride; float* cbase;
  if (mode == 0) {
    int n = st >> 1;
    int sb = perm[b * NB + n];
    long a_row0 = (long)sb * BS + (st & 1) * 128;
    a_off = (a_row0 * B_ + b) * D_;
    a_stride = (long)B_ * D_;
    cbase = C + ((long)b * S_ + st * 128) * D_;
    c_stride = D_;
  } else {
    a_off = ((long)b * S_ + st * 128) * D_;
    a_stride = D_;
    cbase = C + ((long)(st * 128) * B_ + b) * D_;
    c_stride = (long)B_ * D_;
  }
  const u16* Ah = Ahi + a_off;
  const u16* Al = Alo + a_off;
  __shared__ u16 Ash[128 * 32], Asl[128 * 32], Bsh[128 * 32], Bsl[128 * 32];
  int t = threadIdx.x;
  int w = t >> 6, lane = t & 63, quad = lane >> 4, l15 = lane & 15;
  int wm = w >> 1, wn = w & 1;
  f32x4 acc[4][4];
#pragma unroll
  for (int i = 0; i < 4; ++i)
#pragma unroll
    for (int j = 0; j < 4; ++j) acc[i][j] = {0.f, 0.f, 0.f, 0.f};

  int idx0 = t * 8, idx1 = t * 8 + 2048;
  int r0 = idx0 >> 5, c0 = idx0 & 31;
  int r1 = idx1 >> 5, c1 = idx1 & 31;
  for (int k0 = 0; k0 < D_; k0 += 32) {
    gld_lds16(Ah + (long)r0 * a_stride + k0 + c0, Ash + idx0);
    gld_lds16(Ah + (long)r1 * a_stride + k0 + c1, Ash + idx1);
    gld_lds16(Al + (long)r0 * a_stride + k0 + c0, Asl + idx0);
    gld_lds16(Al + (long)r1 * a_stride + k0 + c1, Asl + idx1);
    gld_lds16(Wh + (long)(col0 + r0) * D_ + k0 + c0, Bsh + idx0);
    gld_lds16(Wh + (long)(col0 + r1) * D_ + k0 + c1, Bsh + idx1);
    gld_lds16(Wl + (long)(col0 + r0) * D_ + k0 + c0, Bsl + idx0);
    gld_lds16(Wl + (long)(col0 + r1) * D_ + k0 + c1, Bsl + idx1);
    __syncthreads();
    bf16x8 ah[4], al[4], bh[4], bl[4];
#pragma unroll
    for (int i = 0; i < 4; ++i) {
      ah[i] = *(const bf16x8*)(Ash + (wm * 64 + i * 16 + l15) * 32 + quad * 8);
      al[i] = *(const bf16x8*)(Asl + (wm * 64 + i * 16 + l15) * 32 + quad * 8);
    }
#pragma unroll
    for (int j = 0; j < 4; ++j) {
      bh[j] = *(const bf16x8*)(Bsh + (wn * 64 + j * 16 + l15) * 32 + quad * 8);
      bl[j] = *(const bf16x8*)(Bsl + (wn * 64 + j * 16 + l15) * 32 + quad * 8);
    }
#pragma unroll
    for (int i = 0; i < 4; ++i)
#pragma unroll
      for (int j = 0; j < 4; ++j) {
        acc[i][j] = __builtin_amdgcn_mfma_f32_16x16x32_bf16(al[i], bh[j], acc[i][j], 0, 0, 0);
        acc[i][j] = __builtin_amdgcn_mfma_f32_16x16x32_bf16(ah[i], bl[j], acc[i][j], 0, 0, 0);
        acc[i][j] = __builtin_amdgcn_mfma_f32_16x16x32_bf16(ah[i], bh[j], acc[i][j], 0, 0, 0);
      }
    __syncthreads();
  }
#pragma unroll
  for (int j = 0; j < 4; ++j) {
    float bv = bi[col0 + wn * 64 + j * 16 + l15];
#pragma unroll
    for (int i = 0; i < 4; ++i) {
      int row = wm * 64 + i * 16 + quad * 4;
      long base = (long)row * c_stride + col0 + wn * 64 + j * 16 + l15;
#pragma unroll
      for (int r = 0; r < 4; ++r)
        cbase[base + (long)r * c_stride] = acc[i][j][r] + bv;
    }
  }
}

// ---------------- block-local attention, fp32, hi/lo epilogue ----------------
// grid: 1024 (all-batch, bfix<0) or 256 (per-batch, bfix=b). 256 threads = 1 q-row each.
__global__ __launch_bounds__(256, 2) void attn_kernel(
    const float* __restrict__ Q, const float* __restrict__ K, const float* __restrict__ V,
    u16* __restrict__ aohi, u16* __restrict__ aolo, int bfix) {
  int b = (bfix >= 0) ? bfix : (int)(blockIdx.x >> 8);
  int n = (blockIdx.x >> 4) & 15, h = blockIdx.x & 15;
  int t = threadIdx.x;
  __shared__ float Kc[64][68];
  __shared__ float Vc[64][68];
  long rbase = (long)b * S_ + n * BS;
  float4 qv[16];
  const float* qrow = Q + (rbase + t) * D_ + h * HD;
#pragma unroll
  for (int e = 0; e < 16; ++e) qv[e] = *(const float4*)(qrow + e * 4);
  float m = -3e38f, l = 0.f;
  float4 o4[16];
#pragma unroll
  for (int e = 0; e < 16; ++e) o4[e] = {0.f, 0.f, 0.f, 0.f};

  int sj = t >> 2, se = (t & 3) * 16;
  for (int c = 0; c < 4; ++c) {
    __syncthreads();
    const float* kp = K + (rbase + c * 64 + sj) * D_ + h * HD + se;
    const float* vp = V + (rbase + c * 64 + sj) * D_ + h * HD + se;
#pragma unroll
    for (int i = 0; i < 4; ++i) {
      *(float4*)&Kc[sj][se + i * 4] = *(const float4*)(kp + i * 4);
      *(float4*)&Vc[sj][se + i * 4] = *(const float4*)(vp + i * 4);
    }
    __syncthreads();
    for (int j = 0; j < 64; ++j) {
      float s = 0.f;
#pragma unroll
      for (int e = 0; e < 16; ++e) {
        float4 kv = *(const float4*)&Kc[j][e * 4];
        s += qv[e].x * kv.x + qv[e].y * kv.y + qv[e].z * kv.z + qv[e].w * kv.w;
      }
      s *= 0.125f;
      if (s > m) {
        float sc = __expf(m - s);
        l *= sc;
#pragma unroll
        for (int e = 0; e < 16; ++e) {
          o4[e].x *= sc; o4[e].y *= sc; o4[e].z *= sc; o4[e].w *= sc;
        }
        m = s;
      }
      float p = __expf(s - m);
      l += p;
#pragma unroll
      for (int e = 0; e < 16; ++e) {
        float4 vv = *(const float4*)&Vc[j][e * 4];
        o4[e].x += p * vv.x; o4[e].y += p * vv.y;
        o4[e].z += p * vv.z; o4[e].w += p * vv.w;
      }
    }
  }
  float inv = 1.f / l;
  u16* oh = aohi + (rbase + t) * D_ + h * HD;
  u16* ol = aolo + (rbase + t) * D_ + h * HD;
#pragma unroll
  for (int e = 0; e < 16; ++e) {
    float f0 = o4[e].x * inv, f1 = o4[e].y * inv, f2 = o4[e].z * inv, f3 = o4[e].w * inv;
    ushort4 hh, ll;
    hh.x = f2bfu(f0); ll.x = f2bfu(f0 - bfu2f(hh.x));
    hh.y = f2bfu(f1); ll.y = f2bfu(f1 - bfu2f(hh.y));
    hh.z = f2bfu(f2); ll.z = f2bfu(f2 - bfu2f(hh.z));
    hh.w = f2bfu(f3); ll.w = f2bfu(f3 - bfu2f(hh.w));
    *(ushort4*)(oh + e * 4) = hh;
    *(ushort4*)(ol + e * 4) = ll;
  }
}

// ================= Tier C fallback (round-2 proven path) =================
__global__ __launch_bounds__(256, 2) void gemm_f32_kernel(
    const float* __restrict__ A0,
    const float* __restrict__ W0, const float* __restrict__ W1, const float* __restrict__ W2,
    const float* __restrict__ bi0, const float* __restrict__ bi1, const float* __restrict__ bi2,
    float* __restrict__ O0, float* __restrict__ O1, float* __restrict__ O2,
    const int* __restrict__ perm, int b, int mode) {
  int z = blockIdx.z;
  const float* W  = (z == 0) ? W0 : (z == 1 ? W1 : W2);
  const float* bi = (z == 0) ? bi0 : (z == 1 ? bi1 : bi2);
  float* C        = (z == 0) ? O0 : (z == 1 ? O1 : O2);
  int st = blockIdx.y;
  int col0 = blockIdx.x * 128;
  const float* abase; float* cbase; long a_stride, c_stride;
  if (mode == 0) {
    int n = st >> 1;
    int sb = perm[b * NB + n];
    long a_row0 = (long)sb * BS + (st & 1) * 128;
    abase = A0 + (a_row0 * B_ + b) * D_;
    a_stride = (long)B_ * D_;
    cbase = C + (long)(st * 128) * D_;
    c_stride = D_;
  } else {
    abase = A0 + (long)(st * 128) * D_;
    a_stride = D_;
    cbase = C + ((long)(st * 128) * B_ + b) * D_;
    c_stride = (long)B_ * D_;
  }
  __shared__ float As[16][132];
  __shared__ float Bs[16][132];
  int t = threadIdx.x;
  int lr = t >> 1, kq = (t & 1) * 8;
  int m0 = (t >> 4) * 8, n0 = (t & 15) * 8;
  const float* aptr = abase + (long)lr * a_stride + kq;
  const float* bptr = W + (long)(col0 + lr) * D_ + kq;
  float acc[8][8];
#pragma unroll
  for (int i = 0; i < 8; ++i)
#pragma unroll
    for (int j = 0; j < 8; ++j) acc[i][j] = 0.f;
  for (int kt = 0; kt < D_ / 16; ++kt) {
    float4 av0 = *(const float4*)(aptr);
    float4 av1 = *(const float4*)(aptr + 4);
    float4 bv0 = *(const float4*)(bptr);
    float4 bv1 = *(const float4*)(bptr + 4);
    aptr += 16; bptr += 16;
    __syncthreads();
    As[kq + 0][lr] = av0.x; As[kq + 1][lr] = av0.y;
    As[kq + 2][lr] = av0.z; As[kq + 3][lr] = av0.w;
    As[kq + 4][lr] = av1.x; As[kq + 5][lr] = av1.y;
    As[kq + 6][lr] = av1.z; As[kq + 7][lr] = av1.w;
    Bs[kq + 0][lr] = bv0.x; Bs[kq + 1][lr] = bv0.y;
    Bs[kq + 2][lr] = bv0.z; Bs[kq + 3][lr] = bv0.w;
    Bs[kq + 4][lr] = bv1.x; Bs[kq + 5][lr] = bv1.y;
    Bs[kq + 6][lr] = bv1.z; Bs[kq + 7][lr] = bv1.w;
    __syncthreads();
#pragma unroll
    for (int k = 0; k < 16; ++k) {
      float4 a0 = *(const float4*)&As[k][m0];
      float4 a1 = *(const float4*)&As[k][m0 + 4];
      float4 b0 = *(const float4*)&Bs[k][n0];
      float4 b1 = *(const float4*)&Bs[k][n0 + 4];
      float aa[8] = {a0.x, a0.y, a0.z, a0.w, a1.x, a1.y, a1.z, a1.w};
      float bb[8] = {b0.x, b0.y, b0.z, b0.w, b1.x, b1.y, b1.z, b1.w};
#pragma unroll
      for (int i = 0; i < 8; ++i)
#pragma unroll
        for (int j = 0; j < 8; ++j) acc[i][j] += aa[i] * bb[j];
    }
  }
  float bb[8];
#pragma unroll
  for (int j = 0; j < 8; ++j) bb[j] = bi[col0 + n0 + j];
#pragma unroll
  for (int i = 0; i < 8; ++i) {
    float* cp = cbase + (long)(m0 + i) * c_stride + col0 + n0;
    float4 c0 = {acc[i][0] + bb[0], acc[i][1] + bb[1], acc[i][2] + bb[2], acc[i][3] + bb[3]};
    float4 c1 = {acc[i][4] + bb[4], acc[i][5] + bb[5], acc[i][6] + bb[6], acc[i][7] + bb[7]};
    *(float4*)(cp) = c0;
    *(float4*)(cp + 4) = c1;
  }
}

__global__ __launch_bounds__(256, 2) void attn_f32_kernel(
    float* __restrict__ Q, const float* __restrict__ K, const float* __restrict__ V) {
  int n = blockIdx.x >> 4, h = blockIdx.x & 15;
  int t = threadIdx.x;
  __shared__ float Kc[64][68];
  __shared__ float Vc[64][68];
  float4 qv[16];
  const float* qrow = Q + ((long)(n * BS) + t) * D_ + h * HD;
#pragma unroll
  for (int e = 0; e < 16; ++e) qv[e] = *(const float4*)(qrow + e * 4);
  float m = -3e38f, l = 0.f;
  float4 o4[16];
#pragma unroll
  for (int e = 0; e < 16; ++e) o4[e] = {0.f, 0.f, 0.f, 0.f};
  int sj = t >> 2, se = (t & 3) * 16;
  for (int c = 0; c < 4; ++c) {
    __syncthreads();
    const float* kp = K + ((long)(n * BS + c * 64 + sj)) * D_ + h * HD + se;
    const float* vp = V + ((long)(n * BS + c * 64 + sj)) * D_ + h * HD + se;
#pragma unroll
    for (int i = 0; i < 4; ++i) {
      *(float4*)&Kc[sj][se + i * 4] = *(const float4*)(kp + i * 4);
      *(float4*)&Vc[sj][se + i * 4] = *(const float4*)(vp + i * 4);
    }
    __syncthreads();
    for (int j = 0; j < 64; ++j) {
      float s = 0.f;
#pragma unroll
      for (int e = 0; e < 16; ++e) {
        float4 kv = *(const float4*)&Kc[j][e * 4];
        s += qv[e].x * kv.x + qv[e].y * kv.y + qv[e].z * kv.z + qv[e].w * kv.w;
      }
      s *= 0.125f;
      if (s > m) {
        float sc = __expf(m - s);
        l *= sc;
#pragma unroll
        for (int e = 0; e < 16; ++e) {
          o4[e].x *= sc; o4[e].y *= sc; o4[e].z *= sc; o4[e].w *= sc;
        }
        m = s;
      }
      float p = __expf(s - m);
      l += p;
#pragma unroll
      for (int e = 0; e < 16; ++e) {
        float4 vv = *(const float4*)&Vc[j][e * 4];
        o4[e].x += p * vv.x; o4[e].y += p * vv.y;
        o4[e].z += p * vv.z; o4[e].w += p * vv.w;
      }
    }
  }
  float inv = 1.f / l;
  float* orow = Q + ((long)(n * BS) + t) * D_ + h * HD;
#pragma unroll
  for (int e = 0; e < 16; ++e) {
    float4 ov = {o4[e].x * inv, o4[e].y * inv, o4[e].z * inv, o4[e].w * inv};
    *(float4*)(orow + e * 4) = ov;
  }
}

// ---------------- launch ----------------
extern "C" void kernel_launch(void* const* d_in, const int* in_sizes, int n_in,
                              void* d_out, int out_size, void* d_ws, size_t ws_size,
                              hipStream_t stream) {
  (void)in_sizes; (void)n_in; (void)out_size;
  const float* x  = (const float*)d_in[0];
  const float* Wq = (const float*)d_in[1];
  const float* bq = (const float*)d_in[2];
  const float* Wk = (const float*)d_in[3];
  const float* bk = (const float*)d_in[4];
  const float* Wv = (const float*)d_in[5];
  const float* bv = (const float*)d_in[6];
  const float* Wo = (const float*)d_in[7];
  const float* bo = (const float*)d_in[8];
  float* out = (float*)d_out;
  char* ws = (char*)d_ws;

  // small shared scratch
  float* xbf  = (float*)(ws);
  float* qbf  = (float*)(ws + 262144);
  float* kbf  = (float*)(ws + 524288);
  float* lgf  = (float*)(ws + 786432);
  int*   perm = (int*)(ws + 790528);

  const size_t NX = (size_t)S_ * B_ * D_;        // 16,777,216 elems
  const size_t NW = (size_t)D_ * D_;             // 1,048,576 elems
  const size_t SM = 1 << 20;

  // routing path (common to all tiers)
  block_mean_kernel<<<64, 256, 0, stream>>>(x, xbf);
  qkblk_kernel<<<128, 256, 0, stream>>>(xbf, Wq, bq, Wk, bk, qbf, kbf);
  logits_kernel<<<256, 256, 0, stream>>>(qbf, kbf, lgf);
  sinkhorn_kernel<<<4, 256, 0, stream>>>(lgf, perm);

  const size_t needA = SM + 2 * NX * 2 + 8 * NW * 2 + 3 * NX * 4 + 2 * NX * 2;
  const size_t needB = SM + 2 * NX * 2 + 8 * NW * 2 + 3 * (NX / B_) * 4 + 2 * (NX / B_) * 2;

  if (ws_size >= needA || ws_size >= needB) {
    int full = (ws_size >= needA);
    size_t off = SM;
    u16* xhi = (u16*)(ws + off); off += NX * 2;
    u16* xlo = (u16*)(ws + off); off += NX * 2;
    u16* whi = (u16*)(ws + off); off += 3 * NW * 2;   // [Wq|Wk|Wv] hi
    u16* wlo = (u16*)(ws + off); off += 3 * NW * 2;
    u16* wohi = (u16*)(ws + off); off += NW * 2;
    u16* wolo = (u16*)(ws + off); off += NW * 2;
    size_t nQ = full ? NX : (NX / B_);
    float* Qf = (float*)(ws + off); off += nQ * 4;
    float* Kf = (float*)(ws + off); off += nQ * 4;
    float* Vf = (float*)(ws + off); off += nQ * 4;
    u16* aohi = (u16*)(ws + off); off += nQ * 2;
    u16* aolo = (u16*)(ws + off); off += nQ * 2;

    split_kernel<<<(int)(NX / 4 / 256), 256, 0, stream>>>(x, xhi, xlo, (int)(NX / 4));
    split_kernel<<<(int)(NW / 4 / 256), 256, 0, stream>>>(Wq, whi, wlo, (int)(NW / 4));
    split_kernel<<<(int)(NW / 4 / 256), 256, 0, stream>>>(Wk, whi + NW, wlo + NW, (int)(NW / 4));
    split_kernel<<<(int)(NW / 4 / 256), 256, 0, stream>>>(Wv, whi + 2 * NW, wlo + 2 * NW, (int)(NW / 4));
    split_kernel<<<(int)(NW / 4 / 256), 256, 0, stream>>>(Wo, wohi, wolo, (int)(NW / 4));

    if (full) {
      gemm_split_kernel<<<dim3(8, 128, 3), 256, 0, stream>>>(
          xhi, xlo, whi, wlo, bq, bk, bv, Qf, Kf, Vf, perm, 0, -1);
      attn_kernel<<<1024, 256, 0, stream>>>(Qf, Kf, Vf, aohi, aolo, -1);
      gemm_split_kernel<<<dim3(8, 128, 1), 256, 0, stream>>>(
          aohi, aolo, wohi, wolo, bo, bo, bo, out, out, out, perm, 1, -1);
    } else {
      for (int b = 0; b < B_; ++b) {
        long sh = (long)b * S_ * D_;     // pointer-offset trick: kernel adds +b*S*D
        float* Qa = Qf - sh; float* Ka = Kf - sh; float* Va = Vf - sh;
        u16* ahA = aohi - sh; u16* alA = aolo - sh;
        gemm_split_kernel<<<dim3(8, 32, 3), 256, 0, stream>>>(
            xhi, xlo, whi, wlo, bq, bk, bv, Qa, Ka, Va, perm, 0, b);
        attn_kernel<<<256, 256, 0, stream>>>(Qa, Ka, Va, ahA, alA, b);
        gemm_split_kernel<<<dim3(8, 32, 1), 256, 0, stream>>>(
            ahA, alA, wohi, wolo, bo, bo, bo, out, out, out, perm, 1, b);
      }
    }
  } else {
    // Tier C: round-2 proven fp32 path (49 MB)
    float* Qb = (float*)(ws + SM);
    float* Kb = Qb + (size_t)S_ * D_;
    float* Vb = Kb + (size_t)S_ * D_;
    for (int b = 0; b < B_; ++b) {
      gemm_f32_kernel<<<dim3(8, 32, 3), 256, 0, stream>>>(
          x, Wq, Wk, Wv, bq, bk, bv, Qb, Kb, Vb, perm, b, 0);
      attn_f32_kernel<<<256, 256, 0, stream>>>(Qb, Kb, Vb);
      gemm_f32_kernel<<<dim3(8, 32, 1), 256, 0, stream>>>(
          Qb, Wo, Wo, Wo, bo, bo, bo, out, out, out, perm, b, 1);
    }
  }
}

// Round 4
// 1088.824 us; speedup vs baseline: 2.5093x; 1.4559x over previous
//
#include <hip/hip_runtime.h>
#include <math.h>

typedef unsigned short u16;
typedef __bf16 bf16t;
typedef bf16t bf16x8 __attribute__((ext_vector_type(8)));
typedef u16 u16x8 __attribute__((ext_vector_type(8)));
typedef float f32x4 __attribute__((ext_vector_type(4)));

#define D_ 1024
#define S_ 4096
#define B_ 4
#define NB 16
#define BS 256
#define NH 16
#define HD 64

__device__ __forceinline__ float bfu2f(u16 u) {
  unsigned int x = ((unsigned int)u) << 16;
  float f; __builtin_memcpy(&f, &x, 4); return f;
}
__device__ __forceinline__ u16 f2bfu(float f) {
  unsigned int x; __builtin_memcpy(&x, &f, 4);
  x += 0x7fffu + ((x >> 16) & 1u);   // RNE
  return (u16)(x >> 16);
}
__device__ __forceinline__ void gld_lds16(const void* g, void* l) {
  __builtin_amdgcn_global_load_lds((__attribute__((address_space(1))) void*)g,
                                   (__attribute__((address_space(3))) void*)l, 16, 0, 0);
}

// ---------------- block means, two-stage ----------------
// stage1: 512 blocks = (b*16+n, p), p=0..7 partial over 32 rows -> xbp[512][1024]
__global__ __launch_bounds__(256) void mean1_kernel(const float* __restrict__ x,
                                                    float* __restrict__ xbp) {
  int bx = blockIdx.x;
  int o = bx >> 3, p = bx & 7;
  int b = o >> 4, n = o & 15;
  int t = threadIdx.x;
  float4 acc = {0.f, 0.f, 0.f, 0.f};
  const float* xp = x + ((long)(n * BS + p * 32) * B_ + b) * D_ + t * 4;
  for (int s = 0; s < 32; ++s) {
    float4 u = *(const float4*)xp;
    acc.x += u.x; acc.y += u.y; acc.z += u.z; acc.w += u.w;
    xp += B_ * D_;
  }
  *(float4*)(xbp + (long)bx * D_ + t * 4) = acc;
}
// stage2: 64 blocks
__global__ __launch_bounds__(256) void mean2_kernel(const float* __restrict__ xbp,
                                                    float* __restrict__ xb) {
  int o = blockIdx.x, t = threadIdx.x;
  float4 acc = {0.f, 0.f, 0.f, 0.f};
#pragma unroll
  for (int p = 0; p < 8; ++p) {
    float4 u = *(const float4*)(xbp + (long)(o * 8 + p) * D_ + t * 4);
    acc.x += u.x; acc.y += u.y; acc.z += u.z; acc.w += u.w;
  }
  float4 r = {acc.x * (1.f / BS), acc.y * (1.f / BS), acc.z * (1.f / BS), acc.w * (1.f / BS)};
  *(float4*)(xb + (long)o * D_ + t * 4) = r;
}

// ---------------- q_blk / k_blk v2: 64 blocks, 64x32 tile each ----------------
__global__ __launch_bounds__(256) void qkblk2_kernel(const float* __restrict__ xb,
    const float* __restrict__ Wq, const float* __restrict__ bq,
    const float* __restrict__ Wk, const float* __restrict__ bk,
    float* __restrict__ qb, float* __restrict__ kb) {
  int m = blockIdx.x >> 5, ct = blockIdx.x & 31;      // m: 0=q 1=k; cols ct*32..+31
  const float* W  = m ? Wk : Wq;
  const float* bi = m ? bk : bq;
  float* out      = m ? kb : qb;
  __shared__ float As[64][132];
  __shared__ float Ws[32][132];
  int t = threadIdx.x;
  int col = t & 31, rg = t >> 5;                      // thread: col, rows rg*8..+7
  float acc[8];
#pragma unroll
  for (int i = 0; i < 8; ++i) acc[i] = 0.f;
  int srow = t >> 2, sks = (t & 3) * 32;
  for (int kc = 0; kc < 8; ++kc) {
    int k0 = kc * 128;
    __syncthreads();
#pragma unroll
    for (int j = 0; j < 8; ++j)
      *(float4*)&As[srow][sks + j * 4] = *(const float4*)(xb + (long)srow * D_ + k0 + sks + j * 4);
    if (t < 128) {
      int c = t >> 2, ks = (t & 3) * 32;
#pragma unroll
      for (int j = 0; j < 8; ++j)
        *(float4*)&Ws[c][ks + j * 4] =
            *(const float4*)(W + (long)(ct * 32 + c) * D_ + k0 + ks + j * 4);
    }
    __syncthreads();
#pragma unroll
    for (int k4 = 0; k4 < 32; ++k4) {
      float4 wv = *(const float4*)&Ws[col][k4 * 4];
#pragma unroll
      for (int i = 0; i < 8; ++i) {
        float4 av = *(const float4*)&As[rg * 8 + i][k4 * 4];
        acc[i] += av.x * wv.x + av.y * wv.y + av.z * wv.z + av.w * wv.w;
      }
    }
  }
  float bv = bi[ct * 32 + col];
#pragma unroll
  for (int i = 0; i < 8; ++i)
    out[(long)(rg * 8 + i) * D_ + ct * 32 + col] = acc[i] + bv;
}

// ---------------- logits ----------------
__global__ __launch_bounds__(256) void logits_kernel(const float* __restrict__ qb,
                                                     const float* __restrict__ kb,
                                                     float* __restrict__ lg) {
  int idx = blockIdx.x * 4 + (threadIdx.x >> 6);
  int b = idx >> 8, n = (idx >> 4) & 15, m = idx & 15;
  int lane = threadIdx.x & 63;
  float acc = 0.f;
  const float* qp = qb + (b * 16 + n) * D_ + lane;
  const float* kp = kb + (b * 16 + m) * D_ + lane;
#pragma unroll
  for (int kk = 0; kk < 16; ++kk) acc += qp[kk * 64] * kp[kk * 64];
#pragma unroll
  for (int mm = 1; mm < 64; mm <<= 1) acc += __shfl_xor(acc, mm);
  if (lane == 0) lg[idx] = acc * (1.f / 32.f);
}

// ---------------- Sinkhorn + argmax ----------------
__global__ __launch_bounds__(256) void sinkhorn_kernel(const float* __restrict__ lg,
                                                       int* __restrict__ perm) {
  int b = blockIdx.x;
  __shared__ float L[16][17];
  int t = threadIdx.x;
  int n = t >> 4, m = t & 15;
  L[n][m] = lg[b * 256 + t];
  __syncthreads();
  for (int it = 0; it < 5; ++it) {
    float mx = -3e38f;
#pragma unroll
    for (int i = 0; i < 16; ++i) mx = fmaxf(mx, L[n][i]);
    float sm = 0.f;
#pragma unroll
    for (int i = 0; i < 16; ++i) sm += expf(L[n][i] - mx);
    float lse = mx + logf(sm);
    __syncthreads();
    L[n][m] -= lse;
    __syncthreads();
    mx = -3e38f;
#pragma unroll
    for (int i = 0; i < 16; ++i) mx = fmaxf(mx, L[i][m]);
    sm = 0.f;
#pragma unroll
    for (int i = 0; i < 16; ++i) sm += expf(L[i][m] - mx);
    lse = mx + logf(sm);
    __syncthreads();
    L[n][m] -= lse;
    __syncthreads();
  }
  if (t < 16) {
    float best = -3e38f; int bi = 0;
#pragma unroll
    for (int i = 0; i < 16; ++i) {
      float v = L[t][i];
      if (v > best) { best = v; bi = i; }
    }
    perm[b * 16 + t] = bi;
  }
}

// ---------------- merged weight split: 4 matrices -> hi/lo bf16 ----------------
__global__ __launch_bounds__(256) void wsplit_kernel(
    const float* __restrict__ Wq, const float* __restrict__ Wk,
    const float* __restrict__ Wv, const float* __restrict__ Wo,
    u16* __restrict__ whi, u16* __restrict__ wlo,
    u16* __restrict__ wohi, u16* __restrict__ wolo) {
  const size_t NW = (size_t)D_ * D_;
  int z = blockIdx.y;
  const float* src = (z == 0) ? Wq : (z == 1) ? Wk : (z == 2) ? Wv : Wo;
  u16* dh = (z < 3) ? (whi + (size_t)z * NW) : wohi;
  u16* dl = (z < 3) ? (wlo + (size_t)z * NW) : wolo;
  long i = (long)blockIdx.x * 256 + threadIdx.x;
  float4 v = ((const float4*)src)[i];
  ushort4 h, l;
  h.x = f2bfu(v.x); l.x = f2bfu(v.x - bfu2f(h.x));
  h.y = f2bfu(v.y); l.y = f2bfu(v.y - bfu2f(h.y));
  h.z = f2bfu(v.z); l.z = f2bfu(v.z - bfu2f(h.z));
  h.w = f2bfu(v.w); l.w = f2bfu(v.w - bfu2f(h.w));
  ((ushort4*)dh)[i] = h;
  ((ushort4*)dl)[i] = l;
}

// ---------------- QKV GEMM: C = gather(x) @ W^T + bias, split-bf16 MFMA ----------
// A = x fp32 (S,B,D) with perm gather, split to hi/lo in-kernel.
// grid (8, 64, 3): x=col-tile, y = g(2)*32+st, z = {q,k,v}. C fp32 (2,S,D) per group.
__global__ __launch_bounds__(256, 2) void gemm_qkv_kernel(
    const float* __restrict__ x,
    const u16* __restrict__ whi, const u16* __restrict__ wlo,
    const float* __restrict__ bq, const float* __restrict__ bk, const float* __restrict__ bv,
    float* __restrict__ Q, float* __restrict__ K, float* __restrict__ V,
    const int* __restrict__ perm, int grp) {
  int z = blockIdx.z;
  const u16* Wh = whi + (size_t)z * (D_ * D_);
  const u16* Wl = wlo + (size_t)z * (D_ * D_);
  const float* bi = (z == 0) ? bq : (z == 1) ? bk : bv;
  float* C        = (z == 0) ? Q : (z == 1) ? K : V;
  int g = blockIdx.y >> 5, st = blockIdx.y & 31;
  int b = grp * 2 + g;
  int col0 = blockIdx.x * 128;
  int n = st >> 1;
  int sb = perm[b * NB + n];
  const float* abase = x + ((long)(sb * BS + (st & 1) * 128) * B_ + b) * D_;
  const long a_stride = (long)B_ * D_;
  float* cbase = C + ((long)g * S_ + st * 128) * D_;

  __shared__ u16 Ash[128 * 32], Asl[128 * 32], Bsh[128 * 32], Bsl[128 * 32];
  int t = threadIdx.x;
  int w = t >> 6, lane = t & 63, quad = lane >> 4, l15 = lane & 15;
  int wm = w >> 1, wn = w & 1;
  f32x4 acc[4][4];
#pragma unroll
  for (int i = 0; i < 4; ++i)
#pragma unroll
    for (int j = 0; j < 4; ++j) acc[i][j] = {0.f, 0.f, 0.f, 0.f};

  int idx0 = t * 8, idx1 = t * 8 + 2048;
  int ar0 = idx0 >> 5, ac0 = idx0 & 31;
  int ar1 = idx1 >> 5, ac1 = idx1 & 31;
  for (int k0 = 0; k0 < D_; k0 += 32) {
    // B operands: async global->LDS (bf16 pre-split)
    gld_lds16(Wh + (long)(col0 + ar0) * D_ + k0 + ac0, Bsh + idx0);
    gld_lds16(Wh + (long)(col0 + ar1) * D_ + k0 + ac1, Bsh + idx1);
    gld_lds16(Wl + (long)(col0 + ar0) * D_ + k0 + ac0, Bsl + idx0);
    gld_lds16(Wl + (long)(col0 + ar1) * D_ + k0 + ac1, Bsl + idx1);
    // A operand: fp32 load, in-register hi/lo split, LDS store
#pragma unroll
    for (int c = 0; c < 2; ++c) {
      int idx = t * 8 + c * 2048;
      int r = idx >> 5, kc = idx & 31;
      const float* ga = abase + (long)r * a_stride + k0 + kc;
      f32x4 v0 = *(const f32x4*)ga;
      f32x4 v1 = *(const f32x4*)(ga + 4);
      u16x8 hv, lv;
#pragma unroll
      for (int j = 0; j < 4; ++j) {
        u16 h0 = f2bfu(v0[j]); hv[j] = h0;     lv[j] = f2bfu(v0[j] - bfu2f(h0));
        u16 h1 = f2bfu(v1[j]); hv[j + 4] = h1; lv[j + 4] = f2bfu(v1[j] - bfu2f(h1));
      }
      *(u16x8*)(Ash + idx) = hv;
      *(u16x8*)(Asl + idx) = lv;
    }
    __syncthreads();
    bf16x8 ah[4], al[4], bh[4], bl[4];
#pragma unroll
    for (int i = 0; i < 4; ++i) {
      ah[i] = *(const bf16x8*)(Ash + (wm * 64 + i * 16 + l15) * 32 + quad * 8);
      al[i] = *(const bf16x8*)(Asl + (wm * 64 + i * 16 + l15) * 32 + quad * 8);
    }
#pragma unroll
    for (int j = 0; j < 4; ++j) {
      bh[j] = *(const bf16x8*)(Bsh + (wn * 64 + j * 16 + l15) * 32 + quad * 8);
      bl[j] = *(const bf16x8*)(Bsl + (wn * 64 + j * 16 + l15) * 32 + quad * 8);
    }
#pragma unroll
    for (int i = 0; i < 4; ++i)
#pragma unroll
      for (int j = 0; j < 4; ++j) {
        acc[i][j] = __builtin_amdgcn_mfma_f32_16x16x32_bf16(al[i], bh[j], acc[i][j], 0, 0, 0);
        acc[i][j] = __builtin_amdgcn_mfma_f32_16x16x32_bf16(ah[i], bl[j], acc[i][j], 0, 0, 0);
        acc[i][j] = __builtin_amdgcn_mfma_f32_16x16x32_bf16(ah[i], bh[j], acc[i][j], 0, 0, 0);
      }
    __syncthreads();
  }
#pragma unroll
  for (int j = 0; j < 4; ++j) {
    float bvv = bi[col0 + wn * 64 + j * 16 + l15];
#pragma unroll
    for (int i = 0; i < 4; ++i) {
      int row = wm * 64 + i * 16 + quad * 4;
      long base = (long)row * D_ + col0 + wn * 64 + j * 16 + l15;
#pragma unroll
      for (int r = 0; r < 4; ++r)
        cbase[base + (long)r * D_] = acc[i][j][r] + bvv;
    }
  }
}

// ---------------- out GEMM: out = ao @ Wo^T + bo, A = hi/lo bf16 ----------------
// grid (8, 64): y = g*32+st. A (2,S,D) hi/lo; C = out (S,B,D) fp32 at b=grp*2+g.
__global__ __launch_bounds__(256, 2) void gemm_out_kernel(
    const u16* __restrict__ Ahi, const u16* __restrict__ Alo,
    const u16* __restrict__ wohi, const u16* __restrict__ wolo,
    const float* __restrict__ bo, float* __restrict__ out, int grp) {
  int g = blockIdx.y >> 5, st = blockIdx.y & 31;
  int b = grp * 2 + g;
  int col0 = blockIdx.x * 128;
  long a_off = ((long)g * S_ + st * 128) * D_;
  const u16* Ah = Ahi + a_off;
  const u16* Al = Alo + a_off;
  float* cbase = out + ((long)(st * 128) * B_ + b) * D_;
  const long c_stride = (long)B_ * D_;

  __shared__ u16 Ash[128 * 32], Asl[128 * 32], Bsh[128 * 32], Bsl[128 * 32];
  int t = threadIdx.x;
  int w = t >> 6, lane = t & 63, quad = lane >> 4, l15 = lane & 15;
  int wm = w >> 1, wn = w & 1;
  f32x4 acc[4][4];
#pragma unroll
  for (int i = 0; i < 4; ++i)
#pragma unroll
    for (int j = 0; j < 4; ++j) acc[i][j] = {0.f, 0.f, 0.f, 0.f};

  int idx0 = t * 8, idx1 = t * 8 + 2048;
  int r0 = idx0 >> 5, c0 = idx0 & 31;
  int r1 = idx1 >> 5, c1 = idx1 & 31;
  for (int k0 = 0; k0 < D_; k0 += 32) {
    gld_lds16(Ah + (long)r0 * D_ + k0 + c0, Ash + idx0);
    gld_lds16(Ah + (long)r1 * D_ + k0 + c1, Ash + idx1);
    gld_lds16(Al + (long)r0 * D_ + k0 + c0, Asl + idx0);
    gld_lds16(Al + (long)r1 * D_ + k0 + c1, Asl + idx1);
    gld_lds16(wohi + (long)(col0 + r0) * D_ + k0 + c0, Bsh + idx0);
    gld_lds16(wohi + (long)(col0 + r1) * D_ + k0 + c1, Bsh + idx1);
    gld_lds16(wolo + (long)(col0 + r0) * D_ + k0 + c0, Bsl + idx0);
    gld_lds16(wolo + (long)(col0 + r1) * D_ + k0 + c1, Bsl + idx1);
    __syncthreads();
    bf16x8 ah[4], al[4], bh[4], bl[4];
#pragma unroll
    for (int i = 0; i < 4; ++i) {
      ah[i] = *(const bf16x8*)(Ash + (wm * 64 + i * 16 + l15) * 32 + quad * 8);
      al[i] = *(const bf16x8*)(Asl + (wm * 64 + i * 16 + l15) * 32 + quad * 8);
    }
#pragma unroll
    for (int j = 0; j < 4; ++j) {
      bh[j] = *(const bf16x8*)(Bsh + (wn * 64 + j * 16 + l15) * 32 + quad * 8);
      bl[j] = *(const bf16x8*)(Bsl + (wn * 64 + j * 16 + l15) * 32 + quad * 8);
    }
#pragma unroll
    for (int i = 0; i < 4; ++i)
#pragma unroll
      for (int j = 0; j < 4; ++j) {
        acc[i][j] = __builtin_amdgcn_mfma_f32_16x16x32_bf16(al[i], bh[j], acc[i][j], 0, 0, 0);
        acc[i][j] = __builtin_amdgcn_mfma_f32_16x16x32_bf16(ah[i], bl[j], acc[i][j], 0, 0, 0);
        acc[i][j] = __builtin_amdgcn_mfma_f32_16x16x32_bf16(ah[i], bh[j], acc[i][j], 0, 0, 0);
      }
    __syncthreads();
  }
#pragma unroll
  for (int j = 0; j < 4; ++j) {
    float bvv = bo[col0 + wn * 64 + j * 16 + l15];
#pragma unroll
    for (int i = 0; i < 4; ++i) {
      int row = wm * 64 + i * 16 + quad * 4;
      long base = (long)row * c_stride + col0 + wn * 64 + j * 16 + l15;
#pragma unroll
      for (int r = 0; r < 4; ++r)
        cbase[base + (long)r * c_stride] = acc[i][j][r] + bvv;
    }
  }
}

// ---------------- block-local attention, fp32, hi/lo epilogue ----------------
// grid 512 = (g, n, h) per 2-batch group; 256 threads = 1 q-row each.
__global__ __launch_bounds__(256, 2) void attn_kernel(
    const float* __restrict__ Q, const float* __restrict__ K, const float* __restrict__ V,
    u16* __restrict__ aohi, u16* __restrict__ aolo) {
  int g = blockIdx.x >> 8;
  int n = (blockIdx.x >> 4) & 15, h = blockIdx.x & 15;
  int t = threadIdx.x;
  __shared__ float Kc[64][68];
  __shared__ float Vc[64][68];
  long rbase = (long)g * S_ + n * BS;
  float4 qv[16];
  const float* qrow = Q + (rbase + t) * D_ + h * HD;
#pragma unroll
  for (int e = 0; e < 16; ++e) qv[e] = *(const float4*)(qrow + e * 4);
  float m = -3e38f, l = 0.f;
  float4 o4[16];
#pragma unroll
  for (int e = 0; e < 16; ++e) o4[e] = {0.f, 0.f, 0.f, 0.f};

  int sj = t >> 2, se = (t & 3) * 16;
  for (int c = 0; c < 4; ++c) {
    __syncthreads();
    const float* kp = K + (rbase + c * 64 + sj) * D_ + h * HD + se;
    const float* vp = V + (rbase + c * 64 + sj) * D_ + h * HD + se;
#pragma unroll
    for (int i = 0; i < 4; ++i) {
      *(float4*)&Kc[sj][se + i * 4] = *(const float4*)(kp + i * 4);
      *(float4*)&Vc[sj][se + i * 4] = *(const float4*)(vp + i * 4);
    }
    __syncthreads();
    for (int j = 0; j < 64; ++j) {
      float s = 0.f;
#pragma unroll
      for (int e = 0; e < 16; ++e) {
        float4 kv = *(const float4*)&Kc[j][e * 4];
        s += qv[e].x * kv.x + qv[e].y * kv.y + qv[e].z * kv.z + qv[e].w * kv.w;
      }
      s *= 0.125f;
      if (s > m) {
        float sc = __expf(m - s);
        l *= sc;
#pragma unroll
        for (int e = 0; e < 16; ++e) {
          o4[e].x *= sc; o4[e].y *= sc; o4[e].z *= sc; o4[e].w *= sc;
        }
        m = s;
      }
      float p = __expf(s - m);
      l += p;
#pragma unroll
      for (int e = 0; e < 16; ++e) {
        float4 vv = *(const float4*)&Vc[j][e * 4];
        o4[e].x += p * vv.x; o4[e].y += p * vv.y;
        o4[e].z += p * vv.z; o4[e].w += p * vv.w;
      }
    }
  }
  float inv = 1.f / l;
  u16* oh = aohi + (rbase + t) * D_ + h * HD;
  u16* ol = aolo + (rbase + t) * D_ + h * HD;
#pragma unroll
  for (int e = 0; e < 16; ++e) {
    float f0 = o4[e].x * inv, f1 = o4[e].y * inv, f2 = o4[e].z * inv, f3 = o4[e].w * inv;
    ushort4 hh, ll;
    hh.x = f2bfu(f0); ll.x = f2bfu(f0 - bfu2f(hh.x));
    hh.y = f2bfu(f1); ll.y = f2bfu(f1 - bfu2f(hh.y));
    hh.z = f2bfu(f2); ll.z = f2bfu(f2 - bfu2f(hh.z));
    hh.w = f2bfu(f3); ll.w = f2bfu(f3 - bfu2f(hh.w));
    *(ushort4*)(oh + e * 4) = hh;
    *(ushort4*)(ol + e * 4) = ll;
  }
}

// ================= Tier C fallback (round-2 proven path) =================
__global__ __launch_bounds__(256, 2) void gemm_f32_kernel(
    const float* __restrict__ A0,
    const float* __restrict__ W0, const float* __restrict__ W1, const float* __restrict__ W2,
    const float* __restrict__ bi0, const float* __restrict__ bi1, const float* __restrict__ bi2,
    float* __restrict__ O0, float* __restrict__ O1, float* __restrict__ O2,
    const int* __restrict__ perm, int b, int mode) {
  int z = blockIdx.z;
  const float* W  = (z == 0) ? W0 : (z == 1 ? W1 : W2);
  const float* bi = (z == 0) ? bi0 : (z == 1 ? bi1 : bi2);
  float* C        = (z == 0) ? O0 : (z == 1 ? O1 : O2);
  int st = blockIdx.y;
  int col0 = blockIdx.x * 128;
  const float* abase; float* cbase; long a_stride, c_stride;
  if (mode == 0) {
    int n = st >> 1;
    int sb = perm[b * NB + n];
    long a_row0 = (long)sb * BS + (st & 1) * 128;
    abase = A0 + (a_row0 * B_ + b) * D_;
    a_stride = (long)B_ * D_;
    cbase = C + (long)(st * 128) * D_;
    c_stride = D_;
  } else {
    abase = A0 + (long)(st * 128) * D_;
    a_stride = D_;
    cbase = C + ((long)(st * 128) * B_ + b) * D_;
    c_stride = (long)B_ * D_;
  }
  __shared__ float As[16][132];
  __shared__ float Bs[16][132];
  int t = threadIdx.x;
  int lr = t >> 1, kq = (t & 1) * 8;
  int m0 = (t >> 4) * 8, n0 = (t & 15) * 8;
  const float* aptr = abase + (long)lr * a_stride + kq;
  const float* bptr = W + (long)(col0 + lr) * D_ + kq;
  float acc[8][8];
#pragma unroll
  for (int i = 0; i < 8; ++i)
#pragma unroll
    for (int j = 0; j < 8; ++j) acc[i][j] = 0.f;
  for (int kt = 0; kt < D_ / 16; ++kt) {
    float4 av0 = *(const float4*)(aptr);
    float4 av1 = *(const float4*)(aptr + 4);
    float4 bv0 = *(const float4*)(bptr);
    float4 bv1 = *(const float4*)(bptr + 4);
    aptr += 16; bptr += 16;
    __syncthreads();
    As[kq + 0][lr] = av0.x; As[kq + 1][lr] = av0.y;
    As[kq + 2][lr] = av0.z; As[kq + 3][lr] = av0.w;
    As[kq + 4][lr] = av1.x; As[kq + 5][lr] = av1.y;
    As[kq + 6][lr] = av1.z; As[kq + 7][lr] = av1.w;
    Bs[kq + 0][lr] = bv0.x; Bs[kq + 1][lr] = bv0.y;
    Bs[kq + 2][lr] = bv0.z; Bs[kq + 3][lr] = bv0.w;
    Bs[kq + 4][lr] = bv1.x; Bs[kq + 5][lr] = bv1.y;
    Bs[kq + 6][lr] = bv1.z; Bs[kq + 7][lr] = bv1.w;
    __syncthreads();
#pragma unroll
    for (int k = 0; k < 16; ++k) {
      float4 a0 = *(const float4*)&As[k][m0];
      float4 a1 = *(const float4*)&As[k][m0 + 4];
      float4 b0 = *(const float4*)&Bs[k][n0];
      float4 b1 = *(const float4*)&Bs[k][n0 + 4];
      float aa[8] = {a0.x, a0.y, a0.z, a0.w, a1.x, a1.y, a1.z, a1.w};
      float bb[8] = {b0.x, b0.y, b0.z, b0.w, b1.x, b1.y, b1.z, b1.w};
#pragma unroll
      for (int i = 0; i < 8; ++i)
#pragma unroll
        for (int j = 0; j < 8; ++j) acc[i][j] += aa[i] * bb[j];
    }
  }
  float bb[8];
#pragma unroll
  for (int j = 0; j < 8; ++j) bb[j] = bi[col0 + n0 + j];
#pragma unroll
  for (int i = 0; i < 8; ++i) {
    float* cp = cbase + (long)(m0 + i) * c_stride + col0 + n0;
    float4 c0 = {acc[i][0] + bb[0], acc[i][1] + bb[1], acc[i][2] + bb[2], acc[i][3] + bb[3]};
    float4 c1 = {acc[i][4] + bb[4], acc[i][5] + bb[5], acc[i][6] + bb[6], acc[i][7] + bb[7]};
    *(float4*)(cp) = c0;
    *(float4*)(cp + 4) = c1;
  }
}

__global__ __launch_bounds__(256, 2) void attn_f32_kernel(
    float* __restrict__ Q, const float* __restrict__ K, const float* __restrict__ V) {
  int n = blockIdx.x >> 4, h = blockIdx.x & 15;
  int t = threadIdx.x;
  __shared__ float Kc[64][68];
  __shared__ float Vc[64][68];
  float4 qv[16];
  const float* qrow = Q + ((long)(n * BS) + t) * D_ + h * HD;
#pragma unroll
  for (int e = 0; e < 16; ++e) qv[e] = *(const float4*)(qrow + e * 4);
  float m = -3e38f, l = 0.f;
  float4 o4[16];
#pragma unroll
  for (int e = 0; e < 16; ++e) o4[e] = {0.f, 0.f, 0.f, 0.f};
  int sj = t >> 2, se = (t & 3) * 16;
  for (int c = 0; c < 4; ++c) {
    __syncthreads();
    const float* kp = K + ((long)(n * BS + c * 64 + sj)) * D_ + h * HD + se;
    const float* vp = V + ((long)(n * BS + c * 64 + sj)) * D_ + h * HD + se;
#pragma unroll
    for (int i = 0; i < 4; ++i) {
      *(float4*)&Kc[sj][se + i * 4] = *(const float4*)(kp + i * 4);
      *(float4*)&Vc[sj][se + i * 4] = *(const float4*)(vp + i * 4);
    }
    __syncthreads();
    for (int j = 0; j < 64; ++j) {
      float s = 0.f;
#pragma unroll
      for (int e = 0; e < 16; ++e) {
        float4 kv = *(const float4*)&Kc[j][e * 4];
        s += qv[e].x * kv.x + qv[e].y * kv.y + qv[e].z * kv.z + qv[e].w * kv.w;
      }
      s *= 0.125f;
      if (s > m) {
        float sc = __expf(m - s);
        l *= sc;
#pragma unroll
        for (int e = 0; e < 16; ++e) {
          o4[e].x *= sc; o4[e].y *= sc; o4[e].z *= sc; o4[e].w *= sc;
        }
        m = s;
      }
      float p = __expf(s - m);
      l += p;
#pragma unroll
      for (int e = 0; e < 16; ++e) {
        float4 vv = *(const float4*)&Vc[j][e * 4];
        o4[e].x += p * vv.x; o4[e].y += p * vv.y;
        o4[e].z += p * vv.z; o4[e].w += p * vv.w;
      }
    }
  }
  float inv = 1.f / l;
  float* orow = Q + ((long)(n * BS) + t) * D_ + h * HD;
#pragma unroll
  for (int e = 0; e < 16; ++e) {
    float4 ov = {o4[e].x * inv, o4[e].y * inv, o4[e].z * inv, o4[e].w * inv};
    *(float4*)(orow + e * 4) = ov;
  }
}

// ---------------- launch ----------------
extern "C" void kernel_launch(void* const* d_in, const int* in_sizes, int n_in,
                              void* d_out, int out_size, void* d_ws, size_t ws_size,
                              hipStream_t stream) {
  (void)in_sizes; (void)n_in; (void)out_size;
  const float* x  = (const float*)d_in[0];
  const float* Wq = (const float*)d_in[1];
  const float* bq = (const float*)d_in[2];
  const float* Wk = (const float*)d_in[3];
  const float* bk = (const float*)d_in[4];
  const float* Wv = (const float*)d_in[5];
  const float* bv = (const float*)d_in[6];
  const float* Wo = (const float*)d_in[7];
  const float* bo = (const float*)d_in[8];
  float* out = (float*)d_out;
  char* ws = (char*)d_ws;

  // small scratch (1 MB region)
  float* xbf  = (float*)(ws);                   // 64x1024
  float* qbf  = (float*)(ws + 262144);
  float* kbf  = (float*)(ws + 524288);
  float* lgf  = (float*)(ws + 786432);
  int*   perm = (int*)(ws + 790528);

  const size_t NW  = (size_t)D_ * D_;           // 1,048,576
  const size_t NG  = (size_t)2 * S_ * D_;       // 8,388,608 elems per 2-batch group
  const size_t SM  = 1 << 20;

  // fast-path layout (total 152,043,520 B — proven available in round 3)
  size_t off = SM;
  u16* whi  = (u16*)(ws + off); off += 3 * NW * 2;
  u16* wlo  = (u16*)(ws + off); off += 3 * NW * 2;
  u16* wohi = (u16*)(ws + off); off += NW * 2;
  u16* wolo = (u16*)(ws + off); off += NW * 2;
  float* Qf = (float*)(ws + off); off += NG * 4;
  float* Kf = (float*)(ws + off); off += NG * 4;
  float* Vf = (float*)(ws + off); off += NG * 4;
  u16* aohi = (u16*)(ws + off); off += NG * 2;
  u16* aolo = (u16*)(ws + off); off += NG * 2;
  const size_t need = off;

  // routing path (xbp partials live in dead Qf space)
  float* xbp = Qf;   // 512 x 1024 f32 = 2 MB (only used when ws covers fast path)
  if (ws_size >= need) {
    mean1_kernel<<<512, 256, 0, stream>>>(x, xbp);
    mean2_kernel<<<64, 256, 0, stream>>>(xbp, xbf);
  } else {
    // tiny fallback staging area for Tier C
    mean1_kernel<<<512, 256, 0, stream>>>(x, (float*)(ws + SM));
    mean2_kernel<<<64, 256, 0, stream>>>((float*)(ws + SM), xbf);
  }
  qkblk2_kernel<<<64, 256, 0, stream>>>(xbf, Wq, bq, Wk, bk, qbf, kbf);
  logits_kernel<<<256, 256, 0, stream>>>(qbf, kbf, lgf);
  sinkhorn_kernel<<<4, 256, 0, stream>>>(lgf, perm);

  if (ws_size >= need) {
    wsplit_kernel<<<dim3(1024, 4), 256, 0, stream>>>(Wq, Wk, Wv, Wo, whi, wlo, wohi, wolo);
    for (int grp = 0; grp < 2; ++grp) {
      gemm_qkv_kernel<<<dim3(8, 64, 3), 256, 0, stream>>>(
          x, whi, wlo, bq, bk, bv, Qf, Kf, Vf, perm, grp);
      attn_kernel<<<512, 256, 0, stream>>>(Qf, Kf, Vf, aohi, aolo);
      gemm_out_kernel<<<dim3(8, 64), 256, 0, stream>>>(
          aohi, aolo, wohi, wolo, bo, out, grp);
    }
  } else {
    // Tier C: proven fp32 path (49 MB)
    float* Qb = (float*)(ws + 4 * SM);
    float* Kb = Qb + (size_t)S_ * D_;
    float* Vb = Kb + (size_t)S_ * D_;
    for (int b = 0; b < B_; ++b) {
      gemm_f32_kernel<<<dim3(8, 32, 3), 256, 0, stream>>>(
          x, Wq, Wk, Wv, bq, bk, bv, Qb, Kb, Vb, perm, b, 0);
      attn_f32_kernel<<<256, 256, 0, stream>>>(Qb, Kb, Vb);
      gemm_f32_kernel<<<dim3(8, 32, 1), 256, 0, stream>>>(
          Qb, Wo, Wo, Wo, bo, bo, bo, out, out, out, perm, b, 1);
    }
  }
}